// Round 6
// baseline (153.777 us; speedup 1.0000x reference)
//
#include <hip/hip_runtime.h>
#include <math.h>

// S4 forward, collapsed: out depends only on conv output at t = L-1.
// P[b,h] = sum_l kk[h,l]*u[b,h,l] + D[h]*u[b,h,L-1],  kk[h,l] = k[h, L-1-l]
// u = relu(data@w1+b1)@w2 + b2   (fused, never materialized)
//
// Locked: 3 plain dispatches (R4/R6: cross-block coordination loses).
// Locked: k_prep fast transcendentals (R11).
// R12 REJECTED (hp-split serialization), R13 REJECTED (forced occupancy ->
//   spill, VGPR=84, 160MB scratch), R14 neutral-negative (micro-scheduling).
// R15: wave-independent k_main -- NO LDS, NO barriers. Phase A computed
//   TRANSPOSED (x1^T = w1-frag(A) x data-frag(B)) so its MFMA C-output IS
//   phase B's A-fragment, via j-relabeling baked into w2P:
//     slot s of k-window ks holds j = (2ks+(s>>2))*16 + (lane>>4)*4 + (s&3)
//   Each wave: 16 l-rows x 64-h quarter x 2 batches, fully independent.
//   Bias b1 folded into phase-A MFMA C-input. Pp = 256 lt partials (8 MB).

#define L_LEN 4096
#define H_DIM 256
#define J_DIM 128
#define DIN   32
#define NSTATE 32

typedef float f32x4 __attribute__((ext_vector_type(4)));
typedef short s16x8 __attribute__((ext_vector_type(8)));

__device__ __forceinline__ short f2bf(float x) {
  union { float f; unsigned u; } a; a.f = x;
  unsigned r = a.u + 0x7fffu + ((a.u >> 16) & 1u);  // RNE
  return (short)(r >> 16);
}

// ============ kernel 1: prep (w1P/w2P bf16 fragments, kkP permuted) ==========
// 1024 blocks: hg = bid>>6 (16 h-groups), lcg = bid&63; each block does
// lc = lcg*4 .. lcg*4+3 (4 l-chunks) with ONE Kc computation.
// kkP layout (floats): idx = ((((c*4+w)*4+ht)*4+rt)*64 + q*16+s15)*4 + r
//   where l = c*64+rt*16+q*4+r, h = w*64+ht*16+s15 -- MFMA C-fragment order.
// w1P[(c*64+L)*8+s]  = bf16(w1[k][j]), k=(L>>4)*8+s, j=c*16+(L&15)  (A-frag)
// w2P[((T*4+ks)*64+M)*8+s] = bf16(w2[j][h]),
//   j=(2ks+(s>>2))*16+((M>>4)<<2)+(s&3), h=T*16+(M&15)              (B-frag)
__global__ __launch_bounds__(256) void k_prep(
    const float* __restrict__ w1, const float* __restrict__ w2,
    const float* __restrict__ log_dt,
    const float* __restrict__ A_re, const float* __restrict__ A_im,
    const float* __restrict__ C_re, const float* __restrict__ C_im,
    float* __restrict__ kkP,
    short* __restrict__ w1P, short* __restrict__ w2P)
{
  const int bid = blockIdx.x, tid = threadIdx.x;
  __shared__ float kcr[512], kci[512];   // Kc for this block's 16-h group

  // ---- elementwise prep: first 144 blocks cover 36864 items ----
  {
    int i = bid * 256 + tid;
    if (i < 4096) {
      int s = i & 7, Lr = (i >> 3) & 63, c = i >> 9;
      int k = ((Lr >> 4) << 3) + s, j = c * 16 + (Lr & 15);
      w1P[i] = f2bf(w1[k * J_DIM + j]);
    } else if (i < 36864) {
      int i2 = i - 4096;
      int s = i2 & 7, M = (i2 >> 3) & 63, ks = (i2 >> 9) & 3, T = i2 >> 11;
      int j = (2 * ks + (s >> 2)) * 16 + ((M >> 4) << 2) + (s & 3);
      int h = T * 16 + (M & 15);
      w2P[i2] = f2bf(w2[j * H_DIM + h]);
    }
  }

  // ---- Kc for this h-group (computed once; reused for 4 lc-chunks) ----
  const int hg = bid >> 6, lcg = bid & 63;
  for (int e = tid; e < 512; e += 256) {
    int n = e & 31, h2 = e >> 5;
    int h = hg * 16 + h2;
    float dt = __expf(log_dt[h]);
    float are = A_re[h * NSTATE + n], aim = A_im[h * NSTATE + n];
    float dr = dt * are, di = dt * aim;
    float ed = __expf(dr);
    float c, s; __sincosf(di, &s, &c);
    float nr = ed * c - 1.f, ni = ed * s;
    float d2 = are * are + aim * aim;
    float qr = (nr * are + ni * aim) / d2;
    float qi = (ni * are - nr * aim) / d2;
    float cr = C_re[h * NSTATE + n], ci = C_im[h * NSTATE + n];
    kcr[n * 16 + h2] = cr * qr - ci * qi;
    kci[n * 16 + h2] = cr * qi + ci * qr;
  }
  __syncthreads();

  // ---- kk(h, L-1-l) for 4 16x16 (l,h) tiles; write permuted ----
  const int hh = tid & 15, lw = tid >> 4;
  const int h = hg * 16 + hh;
  const float dt = __expf(log_dt[h]);
  const float ar  = A_re[h * NSTATE];
  const float aib = A_im[h * NSTATE + 1];
#pragma unroll
  for (int it = 0; it < 4; it++) {
    int lc = lcg * 4 + it;
    int l = lc * 16 + lw;
    float fm = (float)((L_LEN - 1) - l);
    float mag = __expf(dt * ar * fm);
    float th = dt * aib * fm;
    float s1, c1; __sincosf(th, &s1, &c1);
    float cn = 1.f, sn = 0.f, acc = 0.f;
#pragma unroll
    for (int n = 0; n < NSTATE; n++) {
      acc += kcr[n * 16 + hh] * cn - kci[n * 16 + hh] * sn;
      float c2 = cn * c1 - sn * s1;
      sn = sn * c1 + cn * s1;
      cn = c2;
    }
    float val = 2.f * mag * acc;
    int c  = l >> 6, rt = (l >> 4) & 3, q = (l >> 2) & 3, r = l & 3;
    int w  = h >> 6, ht = (h >> 4) & 3, s15 = h & 15;
    kkP[((((c * 4 + w) * 4 + ht) * 4 + rt) * 64 + q * 16 + s15) * 4 + r] = val;
  }
}

// ============ kernel 2: fused MLP + weighted reduce, wave-independent ========
// 4096 blocks x 4 waves, NO LDS, NO barrier. Block: lt = bidx&255 (16 l-rows),
// bp = bidx>>8 (batch pair). Wave = h-quarter Q. Per wave-batch:
//   phase A (8 MFMA): pa[c] = w1f[c] x data-frag + b1   (x1^T, C: col=l,row=j)
//   af rebuild (pure VGPR): af[ks][s] = relu(pa[2ks+(s>>2)][s&3]) as bf16
//   phase B (16 MFMA): acc[ht] += af[ks] x wk[ht][ks]   (C: col=h, row=l)
//   epilogue: P-partial via kv (kkP frag), shfl over quads, store Pp.
// Pp[(lt*32+b)*256 + h] -- exclusive, no atomics.
__global__ __launch_bounds__(256) void k_main(
    const float* __restrict__ data, const float* __restrict__ b1v,
    const float* __restrict__ b2v, const float* __restrict__ Dv,
    const short* __restrict__ w1P, const short* __restrict__ w2P,
    const float* __restrict__ kkP, float* __restrict__ Pp)
{
  const int bidx = blockIdx.x, tid = threadIdx.x;
  const int wave = tid >> 6, lane = tid & 63;
  const int q = lane >> 4, l15 = lane & 15;
  const int lt = bidx & 255;             // l-tile (16 rows)
  const int bp = bidx >> 8;              // batch pair
  const int Q = wave;                    // h-quarter (64 h)

  // ---- per-wave invariants (held in VGPRs, no reloads) ----
  s16x8 w1f[8];
#pragma unroll
  for (int c = 0; c < 8; c++)
    w1f[c] = *(const s16x8*)(w1P + (c * 64 + lane) * 8);

  s16x8 wk[4][4];
#pragma unroll
  for (int ht = 0; ht < 4; ht++)
#pragma unroll
    for (int ks = 0; ks < 4; ks++)
      wk[ht][ks] = *(const s16x8*)(w2P + (((Q * 4 + ht) * 4 + ks) * 64 + lane) * 8);

  const int c_l = lt >> 2, rt = lt & 3;
  f32x4 kv[4];
  float b2h[4], Dh[4];
#pragma unroll
  for (int ht = 0; ht < 4; ht++) {
    kv[ht] = *((const f32x4*)kkP + ((((c_l * 4 + Q) * 4 + ht) * 4 + rt) * 64 + lane));
    int h = Q * 64 + ht * 16 + l15;
    b2h[ht] = b2v[h]; Dh[ht] = Dv[h];
  }

#pragma unroll 1
  for (int bb = 0; bb < 2; bb++) {
    const int b = bp * 2 + bb;

    // data B-frag: col(lane&15)=l-row, k-slots=(lane>>4)*8+s
    const float* dp = data + ((size_t)b * L_LEN + (size_t)(lt * 16 + l15)) * DIN + q * 8;
    f32x4 d0 = *(const f32x4*)dp;
    f32x4 d1 = *(const f32x4*)(dp + 4);
    s16x8 db;
    db[0] = f2bf(d0[0]); db[1] = f2bf(d0[1]); db[2] = f2bf(d0[2]); db[3] = f2bf(d0[3]);
    db[4] = f2bf(d1[0]); db[5] = f2bf(d1[1]); db[6] = f2bf(d1[2]); db[7] = f2bf(d1[3]);

    // ---- phase A: pa[c] = x1^T tile c (+b1 via MFMA C-input) ----
    f32x4 pa[8];
#pragma unroll
    for (int c = 0; c < 8; c++) {
      f32x4 bi = *(const f32x4*)(b1v + c * 16 + q * 4);
      pa[c] = __builtin_amdgcn_mfma_f32_16x16x32_bf16(w1f[c], db, bi, 0, 0, 0);
    }

    // ---- af rebuild: slot s of window ks <- tile 2ks+(s>>2), reg s&3 ----
    s16x8 af[4];
#pragma unroll
    for (int ks = 0; ks < 4; ks++) {
#pragma unroll
      for (int s = 0; s < 8; s++) {
        af[ks][s] = f2bf(fmaxf(pa[2 * ks + (s >> 2)][s & 3], 0.f));
      }
    }

    // ---- phase B: acc[ht] = x1-tile @ w2 quarter (16 MFMA) ----
    f32x4 acc[4];
#pragma unroll
    for (int ht = 0; ht < 4; ht++)
      acc[ht] = (f32x4){0.f, 0.f, 0.f, 0.f};
#pragma unroll
    for (int ks = 0; ks < 4; ks++)
#pragma unroll
      for (int ht = 0; ht < 4; ht++)
        acc[ht] = __builtin_amdgcn_mfma_f32_16x16x32_bf16(af[ks], wk[ht][ks], acc[ht], 0, 0, 0);

    // ---- epilogue: Pp[lt][b][h] = sum_16rows kk*(u+b2) (+ D at l=L-1) ----
#pragma unroll
    for (int ht = 0; ht < 4; ht++) {
      float s = 0.f;
#pragma unroll
      for (int r = 0; r < 4; r++) {
        int l = lt * 16 + q * 4 + r;       // C-layout: row = q*4+r
        float uu = acc[ht][r] + b2h[ht];
        s = fmaf(kv[ht][r], uu, s);
        if (l == L_LEN - 1) s = fmaf(Dh[ht], uu, s);
      }
      s += __shfl_xor(s, 16, 64);
      s += __shfl_xor(s, 32, 64);
      if (q == 0) Pp[(size_t)(lt * 32 + b) * H_DIM + Q * 64 + ht * 16 + l15] = s;
    }
  }
}

// ============ kernel 3: sum partials -> gelu -> Wg -> GLU -> w3 -> w4 ========
__global__ __launch_bounds__(1024) void k_tail(
    const float* __restrict__ Pp, const float* __restrict__ Wg,
    const float* __restrict__ bgv, const float* __restrict__ w3,
    const float* __restrict__ b3v, const float* __restrict__ w4,
    const float* __restrict__ b4v, float* __restrict__ out)
{
  const int b = blockIdx.x, t = threadIdx.x;
  __shared__ float pp[4][H_DIM];
  __shared__ float g[H_DIM];
  __shared__ float part[2][512];
  __shared__ float glu[H_DIM];
  __shared__ float zp[8][J_DIM];
  __shared__ float zf[J_DIM];

  // ---- P[b,h] = sum over 256 lt partials (4-way split, 64 each) ----
  {
    int h = t & 255, kc = t >> 8;
    float s = 0.f;
#pragma unroll 8
    for (int i = 0; i < 64; i++)
      s += Pp[(size_t)((kc * 64 + i) * 32 + b) * H_DIM + h];
    pp[kc][h] = s;
  }
  __syncthreads();
  if (t < H_DIM) {
    float p = pp[0][t] + pp[1][t] + pp[2][t] + pp[3][t];
    g[t] = 0.5f * p * (1.f + erff(p * 0.70710678118654752f));  // exact gelu
  }
  __syncthreads();

  // y = g @ Wg + bg: 1024 threads = 512 cols x 2-way K-split (128 each)
  {
    int col = t & 511, kc = t >> 9;
    const float* wp = Wg + (size_t)(kc * 128) * 512 + col;
    float acc = 0.f;
#pragma unroll 16
    for (int j = 0; j < 128; j++)
      acc = fmaf(g[kc * 128 + j], wp[(size_t)j * 512], acc);
    part[kc][col] = acc;
  }
  __syncthreads();
  if (t < 512) part[0][t] = bgv[t] + part[0][t] + part[1][t];
  __syncthreads();
  if (t < H_DIM)
    glu[t] = part[0][t] * (1.f / (1.f + expf(-part[0][H_DIM + t])));
  __syncthreads();

  // z = relu(glu @ w3 + b3): 128 cols x 8-way K-split (32 each)
  {
    int col = t & 127, kc = t >> 7;
    const float* wp = w3 + (size_t)(kc * 32) * J_DIM + col;
    float acc = 0.f;
#pragma unroll
    for (int j = 0; j < 32; j++)
      acc = fmaf(glu[kc * 32 + j], wp[(size_t)j * J_DIM], acc);
    zp[kc][col] = acc;
  }
  __syncthreads();
  if (t < J_DIM) {
    float s = b3v[t];
#pragma unroll
    for (int k = 0; k < 8; k++) s += zp[k][t];
    zf[t] = fmaxf(s, 0.f);
  }
  __syncthreads();

  if (t < 16) {
    float s = b4v[t];
#pragma unroll
    for (int i = 0; i < J_DIM; i++)
      s = fmaf(zf[i], w4[i * 16 + t], s);
    out[b * 16 + t] = s;
  }
}

extern "C" void kernel_launch(void* const* d_in, const int* in_sizes, int n_in,
                              void* d_out, int out_size, void* d_ws, size_t ws_size,
                              hipStream_t stream)
{
  const float* data   = (const float*)d_in[0];
  const float* w1     = (const float*)d_in[1];
  const float* b1v    = (const float*)d_in[2];
  const float* w2     = (const float*)d_in[3];
  const float* b2v    = (const float*)d_in[4];
  const float* log_dt = (const float*)d_in[5];
  const float* A_re   = (const float*)d_in[6];
  const float* A_im   = (const float*)d_in[7];
  const float* C_re   = (const float*)d_in[8];
  const float* C_im   = (const float*)d_in[9];
  const float* Dv     = (const float*)d_in[10];
  const float* Wg     = (const float*)d_in[11];
  const float* bgv    = (const float*)d_in[12];
  const float* w3     = (const float*)d_in[13];
  const float* b3v    = (const float*)d_in[14];
  const float* w4     = (const float*)d_in[15];
  const float* b4v    = (const float*)d_in[16];
  float* outp = (float*)d_out;

  // workspace layout (~12.7 MB)
  char* ws = (char*)d_ws;
  float* kkP = (float*)ws;                            // 4 MB (permuted kk)
  float* Pp  = (float*)(ws + 4194304);                // 8 MB (256 x 32 x 256)
  short* w1P = (short*)(ws + 4194304 + 8388608);      // 8 KB
  short* w2P = (short*)(ws + 4194304 + 8388608 + 8192);  // 64 KB

  k_prep<<<1024, 256, 0, stream>>>(w1, w2, log_dt, A_re, A_im, C_re, C_im,
                                   kkP, w1P, w2P);
  k_main<<<4096, 256, 0, stream>>>(data, b1v, b2v, Dv, w1P, w2P, kkP, Pp);
  k_tail<<<32, 1024, 0, stream>>>(Pp, Wg, bgv, w3, b3v, w4, b4v, outp);
}

// Round 7
// 147.036 us; speedup vs baseline: 1.0458x; 1.0458x over previous
//
#include <hip/hip_runtime.h>
#include <math.h>

// S4 forward, collapsed: out depends only on conv output at t = L-1.
// P[b,h] = sum_l kk[h,l]*u[b,h,l] + D[h]*u[b,h,L-1],  kk[h,l] = k[h, L-1-l]
// u = relu(data@w1+b1)@w2 + b2   (fused, never materialized)
//
// Locked: k_main 1024 blocks / 2 batches / LDS-share (512=137.2, 1024=135.9,
//   2048=140.1, hp-split=146.4, forced-occ=176.6(spill), no-LDS waves=153.8).
// Locked: k_prep fast transcendentals (R11).
// R16: k_main reverted to R11-exact. k_tail split: k_act (reduce+gelu, 64blk)
//   -> k_glu (Wg stage via WgT transpose, weights read ONCE: 512KB not 16MB,
//   64blk x 4 waves) -> k_fin (w3/w4 stages, 32blk). Rationale: 256MB poison
//   fill flushes L3 every iteration, so k_tail's 32-block 16MB redundant Wg
//   re-reads were ~20us of HBM at 1/8 BW share.

#define L_LEN 4096
#define H_DIM 256
#define J_DIM 128
#define DIN   32
#define NSTATE 32

typedef float f32x4 __attribute__((ext_vector_type(4)));
typedef short s16x8 __attribute__((ext_vector_type(8)));

__device__ __forceinline__ short f2bf(float x) {
  union { float f; unsigned u; } a; a.f = x;
  unsigned r = a.u + 0x7fffu + ((a.u >> 16) & 1u);  // RNE
  return (short)(r >> 16);
}

// ============ kernel 1: prep (w1T/w2T bf16, kkP permuted, WgT fp32) ==========
// 1024 blocks: hg = bid>>6 (16 h-groups), lcg = bid&63; each block does
// lc = lcg*4 .. lcg*4+3 (4 l-chunks) with ONE Kc computation.
// kkP layout (floats): idx = ((((c*4+w)*4+ht)*4+rt)*64 + q*16+s15)*4 + r
//   where l = c*64+rt*16+q*4+r, h = w*64+ht*16+s15 -- MFMA C-fragment order.
// WgT[c][j] = Wg[j][c]  (512x256 fp32) -- coalesced column access for k_glu.
__global__ __launch_bounds__(256) void k_prep(
    const float* __restrict__ w1, const float* __restrict__ w2,
    const float* __restrict__ Wg,
    const float* __restrict__ log_dt,
    const float* __restrict__ A_re, const float* __restrict__ A_im,
    const float* __restrict__ C_re, const float* __restrict__ C_im,
    float* __restrict__ kkP,
    short* __restrict__ w1T, short* __restrict__ w2T,
    float* __restrict__ WgT)
{
  const int bid = blockIdx.x, tid = threadIdx.x;
  __shared__ float kcr[512], kci[512];   // Kc for this block's 16-h group

  // ---- elementwise prep: first 656 blocks cover 167936 items ----
  {
    int i = bid * 256 + tid;
    if (i < 4096) {
      int n = i >> 5, k = i & 31;        // w1T[n][k] bf16, w1 is (32,128)
      w1T[i] = f2bf(w1[k * J_DIM + n]);
    } else if (i < 36864) {
      int idx = i - 4096;                // w2T[h][k] bf16, w2 is (128,256)
      int h = idx >> 7, k = idx & 127;
      w2T[idx] = f2bf(w2[k * H_DIM + h]);
    } else if (i < 167936) {
      int idx = i - 36864;               // WgT[c][j] fp32, Wg is (256,512)
      int c = idx >> 8, j = idx & 255;
      WgT[idx] = Wg[(size_t)j * 512 + c];
    }
  }

  // ---- Kc for this h-group (computed once; reused for 4 lc-chunks) ----
  const int hg = bid >> 6, lcg = bid & 63;
  for (int e = tid; e < 512; e += 256) {
    int n = e & 31, h2 = e >> 5;
    int h = hg * 16 + h2;
    float dt = __expf(log_dt[h]);
    float are = A_re[h * NSTATE + n], aim = A_im[h * NSTATE + n];
    float dr = dt * are, di = dt * aim;
    float ed = __expf(dr);
    float c, s; __sincosf(di, &s, &c);
    float nr = ed * c - 1.f, ni = ed * s;
    float d2 = are * are + aim * aim;
    float qr = (nr * are + ni * aim) / d2;
    float qi = (ni * are - nr * aim) / d2;
    float cr = C_re[h * NSTATE + n], ci = C_im[h * NSTATE + n];
    kcr[n * 16 + h2] = cr * qr - ci * qi;
    kci[n * 16 + h2] = cr * qi + ci * qr;
  }
  __syncthreads();

  // ---- kk(h, L-1-l) for 4 16x16 (l,h) tiles; write permuted ----
  const int hh = tid & 15, lw = tid >> 4;
  const int h = hg * 16 + hh;
  const float dt = __expf(log_dt[h]);
  const float ar  = A_re[h * NSTATE];
  const float aib = A_im[h * NSTATE + 1];
#pragma unroll
  for (int it = 0; it < 4; it++) {
    int lc = lcg * 4 + it;
    int l = lc * 16 + lw;
    float fm = (float)((L_LEN - 1) - l);
    float mag = __expf(dt * ar * fm);
    float th = dt * aib * fm;
    float s1, c1; __sincosf(th, &s1, &c1);
    float cn = 1.f, sn = 0.f, acc = 0.f;
#pragma unroll
    for (int n = 0; n < NSTATE; n++) {
      acc += kcr[n * 16 + hh] * cn - kci[n * 16 + hh] * sn;
      float c2 = cn * c1 - sn * s1;
      sn = sn * c1 + cn * s1;
      cn = c2;
    }
    float val = 2.f * mag * acc;
    int c  = l >> 6, rt = (l >> 4) & 3, q = (l >> 2) & 3, r = l & 3;
    int w  = h >> 6, ht = (h >> 4) & 3, s15 = h & 15;
    kkP[((((c * 4 + w) * 4 + ht) * 4 + rt) * 64 + q * 16 + s15) * 4 + r] = val;
  }
}

// ============ kernel 2: fused MLP + weighted reduce, 2 batches/block =========
// R11-exact (proven 134.6). 1024 blocks: l0 = (bidx&63)*64, bp = bidx>>6.
// Writes exclusive partials Pp[(lc*32 + b)*256 + h] -- no atomics, no init.
__global__ __launch_bounds__(256) void k_main(
    const float* __restrict__ data, const float* __restrict__ b1v,
    const float* __restrict__ b2v, const float* __restrict__ Dv,
    const short* __restrict__ w1T, const short* __restrict__ w2T,
    const float* __restrict__ kkP, float* __restrict__ Pp)
{
  const int bidx = blockIdx.x, tid = threadIdx.x;
  const int wave = tid >> 6, lane = tid & 63;
  const int quad = lane >> 4, l15 = lane & 15;
  const int bp = bidx >> 6;              // batch pair
  const int lc = bidx & 63;
  const int l0 = lc * 64;

  __shared__ short x1s[2][64 * 136];     // two bf16 x1 tiles (one per batch)

  // ---- Phase A: x1 = relu(data_tile @ w1 + b1) -> LDS, both batches ----
#pragma unroll
  for (int bb = 0; bb < 2; bb++) {
    const int b = bp * 2 + bb;
    const float* dp = data + ((size_t)b * L_LEN + (size_t)(l0 + wave * 16 + l15)) * DIN + quad * 8;
    f32x4 d0 = *(const f32x4*)dp;
    f32x4 d1 = *(const f32x4*)(dp + 4);
    s16x8 af;
    af[0] = f2bf(d0[0]); af[1] = f2bf(d0[1]); af[2] = f2bf(d0[2]); af[3] = f2bf(d0[3]);
    af[4] = f2bf(d1[0]); af[5] = f2bf(d1[1]); af[6] = f2bf(d1[2]); af[7] = f2bf(d1[3]);
#pragma unroll
    for (int c = 0; c < 8; c++) {
      s16x8 bf = *(const s16x8*)(w1T + (c * 16 + l15) * DIN + quad * 8);
      f32x4 a0 = {0.f, 0.f, 0.f, 0.f};
      a0 = __builtin_amdgcn_mfma_f32_16x16x32_bf16(af, bf, a0, 0, 0, 0);
      float bbi = b1v[c * 16 + l15];
#pragma unroll
      for (int r = 0; r < 4; r++) {
        float v = fmaxf(a0[r] + bbi, 0.f);
        x1s[bb][(wave * 16 + quad * 4 + r) * 136 + c * 16 + l15] = f2bf(v);
      }
    }
  }

  // ---- w2 B-fragments in registers (loaded once, reused for both batches) ----
  s16x8 wf[4][4];
#pragma unroll
  for (int ht = 0; ht < 4; ht++)
#pragma unroll
    for (int ks = 0; ks < 4; ks++)
      wf[ht][ks] = *(const s16x8*)(w2T + (wave * 64 + ht * 16 + l15) * J_DIM + ks * 32 + quad * 8);

  __syncthreads();

#pragma unroll 1
  for (int bb = 0; bb < 2; bb++) {
    const int b = bp * 2 + bb;

    f32x4 acc[4][4];
#pragma unroll
    for (int rt = 0; rt < 4; rt++)
#pragma unroll
      for (int ht = 0; ht < 4; ht++)
        acc[rt][ht] = (f32x4){0.f, 0.f, 0.f, 0.f};

    // ---- Phase B: u-tile = x1 @ w2 (64 MFMAs/wave) ----
#pragma unroll
    for (int ks = 0; ks < 4; ks++) {
#pragma unroll
      for (int rt = 0; rt < 4; rt++) {
        s16x8 af = *(const s16x8*)&x1s[bb][(rt * 16 + l15) * 136 + ks * 32 + quad * 8];
#pragma unroll
        for (int ht = 0; ht < 4; ht++)
          acc[rt][ht] = __builtin_amdgcn_mfma_f32_16x16x32_bf16(af, wf[ht][ks], acc[rt][ht], 0, 0, 0);
      }
    }

    // ---- Epilogue: Pp[lc][b][h] = sum_rows kk*(u+b2) (+ D at l=L-1) ----
#pragma unroll
    for (int ht = 0; ht < 4; ht++) {
      int h = wave * 64 + ht * 16 + l15;   // C-layout: col = lane&15
      float b2h = b2v[h], Dh = Dv[h];
      const f32x4* kp = ((const f32x4*)kkP)
                      + (((lc * 4 + wave) * 4 + ht) * 4) * 64 + lane;
      float s = 0.f;
#pragma unroll
      for (int rt = 0; rt < 4; rt++) {
        f32x4 kv = kp[rt * 64];
#pragma unroll
        for (int r = 0; r < 4; r++) {
          int l = l0 + rt * 16 + quad * 4 + r;   // C-layout: row = quad*4+reg
          float uu = acc[rt][ht][r] + b2h;
          s = fmaf(kv[r], uu, s);
          if (l == L_LEN - 1) s = fmaf(Dh, uu, s);
        }
      }
      s += __shfl_xor(s, 16, 64);
      s += __shfl_xor(s, 32, 64);
      if (quad == 0) Pp[(size_t)(lc * 32 + b) * H_DIM + h] = s;
    }
  }
}

// ============ kernel 3a: Pp reduce + exact gelu -> g (32x256) ================
// 64 blocks x 128 thr: one (b,h) per thread; 64 coalesced row-loads each.
__global__ __launch_bounds__(128) void k_act(
    const float* __restrict__ Pp, float* __restrict__ g)
{
  int idx = blockIdx.x * 128 + threadIdx.x;    // 8192 = 32 b x 256 h
  int h = idx & 255, b = idx >> 8;
  float s = 0.f;
#pragma unroll 8
  for (int i = 0; i < 64; i++)
    s += Pp[(size_t)(i * 32 + b) * H_DIM + h];
  g[b * H_DIM + h] = 0.5f * s * (1.f + erff(s * 0.70710678118654752f));
}

// ============ kernel 3b: y = g@Wg+bg, GLU -> glu (32x256) ====================
// 64 blocks x 4 waves; wave = one col-pair (p, p+256) for ALL 32 batches.
// Wg read ONCE total (via WgT): 512 KB, not 32x redundant.
__global__ __launch_bounds__(256) void k_glu(
    const float* __restrict__ g, const float* __restrict__ WgT,
    const float* __restrict__ bgv, float* __restrict__ glu)
{
  const int wave = threadIdx.x >> 6, lane = threadIdx.x & 63;
  const int p = blockIdx.x * 4 + wave;         // 0..255 (a-col index)
  const int b = lane & 31, half = lane >> 5;
  const int col = p + half * 256;              // a-col or paired b-col
  const float* wrow = WgT + (size_t)col * 256; // coalesced row of WgT
  const float* grow = g + b * 256;
  float acc = 0.f;
#pragma unroll 8
  for (int j = 0; j < 256; j++)
    acc = fmaf(grow[j], wrow[j], acc);
  acc += bgv[col];
  float other = __shfl(acc, lane + 32, 64);    // lane<32 gets its b-col value
  if (half == 0) {
    float sig = 1.f / (1.f + __expf(-other));
    glu[b * 256 + p] = acc * sig;
  }
}

// ============ kernel 3c: z = relu(glu@w3+b3); out = z@w4+b4 ==================
__global__ __launch_bounds__(1024) void k_fin(
    const float* __restrict__ glu, const float* __restrict__ w3,
    const float* __restrict__ b3v, const float* __restrict__ w4,
    const float* __restrict__ b4v, float* __restrict__ out)
{
  const int b = blockIdx.x, t = threadIdx.x;
  __shared__ float gl[H_DIM];
  __shared__ float zp[8][J_DIM];
  __shared__ float zf[J_DIM];

  if (t < H_DIM) gl[t] = glu[b * H_DIM + t];
  __syncthreads();

  // z = relu(gl @ w3 + b3): 128 cols x 8-way K-split (32 each)
  {
    int col = t & 127, kc = t >> 7;
    const float* wp = w3 + (size_t)(kc * 32) * J_DIM + col;
    float acc = 0.f;
#pragma unroll
    for (int j = 0; j < 32; j++)
      acc = fmaf(gl[kc * 32 + j], wp[(size_t)j * J_DIM], acc);
    zp[kc][col] = acc;
  }
  __syncthreads();
  if (t < J_DIM) {
    float s = b3v[t];
#pragma unroll
    for (int k = 0; k < 8; k++) s += zp[k][t];
    zf[t] = fmaxf(s, 0.f);
  }
  __syncthreads();

  if (t < 16) {
    float s = b4v[t];
#pragma unroll
    for (int i = 0; i < J_DIM; i++)
      s = fmaf(zf[i], w4[i * 16 + t], s);
    out[b * 16 + t] = s;
  }
}

extern "C" void kernel_launch(void* const* d_in, const int* in_sizes, int n_in,
                              void* d_out, int out_size, void* d_ws, size_t ws_size,
                              hipStream_t stream)
{
  const float* data   = (const float*)d_in[0];
  const float* w1     = (const float*)d_in[1];
  const float* b1v    = (const float*)d_in[2];
  const float* w2     = (const float*)d_in[3];
  const float* b2v    = (const float*)d_in[4];
  const float* log_dt = (const float*)d_in[5];
  const float* A_re   = (const float*)d_in[6];
  const float* A_im   = (const float*)d_in[7];
  const float* C_re   = (const float*)d_in[8];
  const float* C_im   = (const float*)d_in[9];
  const float* Dv     = (const float*)d_in[10];
  const float* Wg     = (const float*)d_in[11];
  const float* bgv    = (const float*)d_in[12];
  const float* w3     = (const float*)d_in[13];
  const float* b3v    = (const float*)d_in[14];
  const float* w4     = (const float*)d_in[15];
  const float* b4v    = (const float*)d_in[16];
  float* outp = (float*)d_out;

  // workspace layout (~6.7 MB)
  char* ws = (char*)d_ws;
  float* kkP = (float*)ws;                        // 4 MB (permuted kk)
  float* Pp  = (float*)(ws + 4194304);            // 2 MB (64 x 32 x 256)
  short* w1T = (short*)(ws + 6291456);            // 8 KB
  short* w2T = (short*)(ws + 6299648);            // 64 KB
  float* WgT = (float*)(ws + 6365184);            // 512 KB (512 x 256 fp32)
  float* g   = (float*)(ws + 6889472);            // 32 KB (32 x 256)
  float* glu = (float*)(ws + 6922240);            // 32 KB (32 x 256)

  k_prep<<<1024, 256, 0, stream>>>(w1, w2, Wg, log_dt, A_re, A_im, C_re, C_im,
                                   kkP, w1T, w2T, WgT);
  k_main<<<1024, 256, 0, stream>>>(data, b1v, b2v, Dv, w1T, w2T, kkP, Pp);
  k_act<<<64, 128, 0, stream>>>(Pp, g);
  k_glu<<<64, 256, 0, stream>>>(g, WgT, bgv, glu);
  k_fin<<<32, 1024, 0, stream>>>(glu, w3, b3v, w4, b4v, outp);
}